// Round 11
// baseline (1193.774 us; speedup 1.0000x reference)
//
#include <hip/hip_runtime.h>
#include <math.h>

#define Tt 128
#define NT 1024
#define EPSF 1e-8f
#define WC_OFF 65536   // u32 offset of C-matmul weights in wsb

typedef _Float16 f16x2 __attribute__((ext_vector_type(2)));

__device__ __forceinline__ float fsigmoid(float v) { return 1.f / (1.f + expf(-v)); }
__device__ __forceinline__ float fsoftplus(float v) { return (v > 20.f) ? v : log1pf(expf(v)); }
__device__ __forceinline__ float ftanh(float v) { float e = expf(2.f * v); return 1.f - 2.f / (e + 1.f); }

__device__ __forceinline__ float dot2(f16x2 a, f16x2 b, float c) {
#if __has_builtin(__builtin_amdgcn_fdot2)
  return __builtin_amdgcn_fdot2(a, b, c, false);
#else
  return c + (float)a.x * (float)b.x + (float)a.y * (float)b.y;
#endif
}
__device__ __forceinline__ f16x2 pack2(float a, float b) {
  f16x2 p; p.x = (_Float16)a; p.y = (_Float16)b; return p;
}

// ---- DPP reduction primitives ----
template <int C> __device__ __forceinline__ float dppadd(float v) {
  int s = __builtin_amdgcn_update_dpp(0, __builtin_bit_cast(int, v), C, 0xf, 0xf, true);
  return v + __builtin_bit_cast(float, s);
}
template <int C> __device__ __forceinline__ float dppmax(float v) {
  int iv = __builtin_bit_cast(int, v);
  int s = __builtin_amdgcn_update_dpp(iv, iv, C, 0xf, 0xf, false);
  return fmaxf(v, __builtin_bit_cast(float, s));
}
__device__ __forceinline__ float halfsum(float v) {
  v = dppadd<0x111>(v); v = dppadd<0x112>(v); v = dppadd<0x114>(v);
  v = dppadd<0x118>(v); v = dppadd<0x142>(v);
  return v;
}
__device__ __forceinline__ float allsum(float v) {
  v = halfsum(v); v = dppadd<0x143>(v);
  return __builtin_bit_cast(float, __builtin_amdgcn_readlane(__builtin_bit_cast(int, v), 63));
}
__device__ __forceinline__ float allmax(float v) {
  v = dppmax<0x111>(v); v = dppmax<0x112>(v); v = dppmax<0x114>(v);
  v = dppmax<0x118>(v); v = dppmax<0x142>(v); v = dppmax<0x143>(v);
  return __builtin_bit_cast(float, __builtin_amdgcn_readlane(__builtin_bit_cast(int, v), 63));
}

// ===== prep: pack weights f32 -> f16x2 streaming layouts =====
// big4 region  [0, 65536):  i = (((c*16+js)*2+q)*64+cg)*4+e
//   jj=q*4+e; row0=js*16+2*jj (h-dim 256); col=(c&1)*64+cg; mat=c>>1 in [We|Wa|Wk0|Wk1]
// wc region [65536, 98304): j = (((c2*16+js)*2+q)*64+cg)*4+e
//   jj=q*4+e; row0=js*16+2*jj (inner [x|r] 256); col=c2*64+cg; rows<128 Wx else Wrd
__global__ __launch_bounds__(256, 1) void ntm_prep(
    const float* __restrict__ We, const float* __restrict__ Wa,
    const float* __restrict__ Wk, const float* __restrict__ Wx,
    const float* __restrict__ Wrd, unsigned int* __restrict__ wsb)
{
  const int i = blockIdx.x * 256 + threadIdx.x;   // grid 384*256 = 98304
  if (i < 65536) {
    const int e = i & 3;
    const int cg = (i >> 2) & 63;
    const int q = (i >> 8) & 1;
    const int js = (i >> 9) & 15;
    const int c = (i >> 13) & 7;
    const int jj = q * 4 + e;
    const int row0 = js * 16 + 2 * jj;
    const int col = (c & 1) * 64 + cg;
    const int mat = c >> 1;
    const float* base = (mat == 0) ? We : (mat == 1) ? Wa : (mat == 2) ? Wk : (Wk + 256 * 128);
    wsb[i] = __builtin_bit_cast(unsigned int, pack2(base[row0 * 128 + col], base[(row0 + 1) * 128 + col]));
  } else {
    const int j = i - WC_OFF;
    const int e = j & 3;
    const int cg = (j >> 2) & 63;
    const int q = (j >> 8) & 1;
    const int js = (j >> 9) & 15;
    const int c2 = (j >> 13) & 3;
    const int jj = q * 4 + e;
    const int row0 = js * 16 + 2 * jj;
    const int col = c2 * 64 + cg;
    float v0, v1;
    if (row0 < 128) { v0 = Wx[row0 * 256 + col]; v1 = Wx[(row0 + 1) * 256 + col]; }
    else            { v0 = Wrd[(row0 - 128) * 256 + col]; v1 = Wrd[(row0 - 127) * 256 + col]; }
    wsb[i] = __builtin_bit_cast(unsigned int, pack2(v0, v1));
  }
}

__global__ __launch_bounds__(NT, 1) void ntm_kernel(
    const float* __restrict__ x, const float* __restrict__ mem0,
    const float* __restrict__ wr0, const float* __restrict__ ww0,
    const float* __restrict__ h0, const float* __restrict__ bh,
    const float* __restrict__ bk,
    const float* __restrict__ Wb, const float* __restrict__ bb,
    const float* __restrict__ Wg, const float* __restrict__ bg,
    const float* __restrict__ Ws, const float* __restrict__ bs,
    const float* __restrict__ Wgam, const float* __restrict__ bgam,
    const float* __restrict__ be, const float* __restrict__ ba,
    const uint4* __restrict__ wsb4,
    float* __restrict__ out)
{
  const int b = blockIdx.x;
  const int t = threadIdx.x;
  const int lane = t & 63;
  const int wave = t >> 6;
  const int cg = t & 63;    // matmul column lane
  const int js = t >> 6;    // inner-dim slice (16 slices of 16)
  const int c4 = t & 31;    // float4 column group for mem passes
  const int rs = t >> 5;    // row slice for mem passes (32 slices)

  __shared__ __align__(16) float mem[128 * 128];   // 64 KB
  __shared__ __align__(16) float part[8192];       // 32 KB
  __shared__ __align__(16) float h_l[256];
  __shared__ __align__(16) float xf[128];
  __shared__ __align__(16) float rf[128];
  __shared__ __align__(16) float er[128];
  __shared__ __align__(16) float ad[128];
  __shared__ __align__(16) float kbuf[256];
  __shared__ float wsm_l[3072];
  __shared__ float wr[128], ww[128];
  __shared__ float normsq[128];
  __shared__ float dotv[256];
  __shared__ float scal[12];
  __shared__ float red2[4];
  __shared__ float bias_big[512];                  // [be | ba | bk0 | bk1]
  __shared__ float bh_l[256];
  __shared__ float bias_sm[12];

  // ===== state / bias / small-weight init =====
  for (int i = t; i < 128 * 128; i += NT) mem[i] = mem0[i];
  if (t < 128) { wr[t] = wr0[b * 128 + t]; ww[t] = ww0[b * 128 + t]; }
  if (t < 256) { h_l[t] = h0[b * 256 + t]; bh_l[t] = bh[t]; }
  if (t < 512) bias_big[t] = (t < 128) ? be[t] : (t < 256) ? ba[t - 128] : bk[t - 256];
  for (int i = t; i < 3072; i += NT) {
    const int d = i >> 8, j = i & 255;
    const int head = d / 6, kind = d % 6;
    float v;
    if (kind == 0)      v = Wb[head * 256 + j];
    else if (kind == 1) v = Wg[head * 256 + j];
    else if (kind == 2) v = Wgam[head * 256 + j];
    else                v = Ws[head * 768 + j * 3 + (kind - 3)];
    wsm_l[i] = v;
  }
  if (t < 12) {
    const int head = t / 6, kind = t % 6;
    bias_sm[t] = (kind == 0) ? bb[head] : (kind == 1) ? bg[head]
               : (kind == 2) ? bgam[head] : bs[head * 3 + (kind - 3)];
  }
  __syncthreads();

  // ---- big4 matmul partials: h from LDS, weights streamed from L2
  auto phase_big4 = [&]() {
    f16x2 hh[8];
    #pragma unroll
    for (int jj = 0; jj < 8; ++jj) {
      const float2 h2 = *reinterpret_cast<const float2*>(&h_l[js * 16 + 2 * jj]);
      hh[jj] = pack2(h2.x, h2.y);
    }
    float acc[8];
    #pragma unroll
    for (int c = 0; c < 8; ++c) acc[c] = 0.f;
    #pragma unroll
    for (int c = 0; c < 8; ++c) {
      const uint4* p = wsb4 + (c * 16 + js) * 128 + cg;
      uint4 w0 = p[0];
      uint4 w1 = p[64];
      acc[c] = dot2(hh[0], __builtin_bit_cast(f16x2, w0.x), acc[c]);
      acc[c] = dot2(hh[1], __builtin_bit_cast(f16x2, w0.y), acc[c]);
      acc[c] = dot2(hh[2], __builtin_bit_cast(f16x2, w0.z), acc[c]);
      acc[c] = dot2(hh[3], __builtin_bit_cast(f16x2, w0.w), acc[c]);
      acc[c] = dot2(hh[4], __builtin_bit_cast(f16x2, w1.x), acc[c]);
      acc[c] = dot2(hh[5], __builtin_bit_cast(f16x2, w1.y), acc[c]);
      acc[c] = dot2(hh[6], __builtin_bit_cast(f16x2, w1.z), acc[c]);
      acc[c] = dot2(hh[7], __builtin_bit_cast(f16x2, w1.w), acc[c]);
    }
    #pragma unroll
    for (int c = 0; c < 8; ++c) part[js * 512 + c * 64 + cg] = acc[c];
  };

  // ---- reduce big4 -> er/ad/kbuf + k^2 (DPP) + 12 small dots (DPP, waves 8-13)
  auto phase_reduce = [&]() {
    if (t < 512) {
      float v = bias_big[t];
      #pragma unroll
      for (int s = 0; s < 16; ++s) v += part[s * 512 + t];
      if (t < 128)      er[t] = fsigmoid(v);
      else if (t < 256) ad[t - 128] = ftanh(v);
      else {
        float kv = ftanh(v);
        kbuf[t - 256] = kv;
        float ks = kv * kv;
        ks = halfsum(ks); ks = dppadd<0x143>(ks);
        if (lane == 63) red2[wave - 4] = ks;
      }
    } else if (t < 896) {
      const int d = (t - 512) >> 5, l5 = t & 31;
      float s = 0.f;
      #pragma unroll
      for (int q = 0; q < 8; ++q) s += h_l[l5 + 32 * q] * wsm_l[d * 256 + l5 + 32 * q];
      s = halfsum(s);
      if ((lane & 31) == 31) scal[d] = s + bias_sm[d];
    }
  };

  // prologue: er/ad/k/scal for step 0 from h0
  phase_big4();
  __syncthreads();
  phase_reduce();
  __syncthreads();

  for (int step = 0; step < Tt; ++step) {
    // ---- P1: x_t -> xf; mem erase/add update; r partials (4 rows/thread)
    if (t < 128) xf[t] = x[((size_t)b * Tt + step) * 128 + t];
    {
      const float4 e4 = *reinterpret_cast<const float4*>(&er[c4 * 4]);
      const float4 a4 = *reinterpret_cast<const float4*>(&ad[c4 * 4]);
      float rx = 0.f, ry = 0.f, rz = 0.f, rw = 0.f;
      #pragma unroll
      for (int k = 0; k < 4; ++k) {
        const int n = rs + 32 * k;
        const float wwn = ww[n], wrn = wr[n];
        float4 v = *reinterpret_cast<const float4*>(&mem[n * 128 + c4 * 4]);
        v.x = v.x * (1.f - wwn * e4.x) + wwn * a4.x;
        v.y = v.y * (1.f - wwn * e4.y) + wwn * a4.y;
        v.z = v.z * (1.f - wwn * e4.z) + wwn * a4.z;
        v.w = v.w * (1.f - wwn * e4.w) + wwn * a4.w;
        *reinterpret_cast<float4*>(&mem[n * 128 + c4 * 4]) = v;
        rx += wrn * v.x; ry += wrn * v.y; rz += wrn * v.z; rw += wrn * v.w;
      }
      *reinterpret_cast<float4*>(&part[rs * 128 + c4 * 4]) = make_float4(rx, ry, rz, rw);
    }
    __syncthreads();  // b1

    // ---- P2: reduce r partials (32 slices)
    if (t < 128) {
      float r = 0.f;
      #pragma unroll
      for (int s = 0; s < 32; ++s) r += part[s * 128 + t];
      rf[t] = r;
    }
    __syncthreads();  // b2

    // ---- P3: C-matmul partials from [xf|rf], weights streamed from L2
    {
      const float* src = (js < 8) ? (xf + js * 16) : (rf + (js - 8) * 16);
      f16x2 xx[8];
      #pragma unroll
      for (int jj = 0; jj < 8; ++jj) {
        const float2 s2 = *reinterpret_cast<const float2*>(&src[2 * jj]);
        xx[jj] = pack2(s2.x, s2.y);
      }
      float acc[4];
      #pragma unroll
      for (int c = 0; c < 4; ++c) acc[c] = 0.f;
      #pragma unroll
      for (int c = 0; c < 4; ++c) {
        const uint4* p = wsb4 + (WC_OFF / 4) + (c * 16 + js) * 128 + cg;
        uint4 w0 = p[0];
        uint4 w1 = p[64];
        acc[c] = dot2(xx[0], __builtin_bit_cast(f16x2, w0.x), acc[c]);
        acc[c] = dot2(xx[1], __builtin_bit_cast(f16x2, w0.y), acc[c]);
        acc[c] = dot2(xx[2], __builtin_bit_cast(f16x2, w0.z), acc[c]);
        acc[c] = dot2(xx[3], __builtin_bit_cast(f16x2, w0.w), acc[c]);
        acc[c] = dot2(xx[4], __builtin_bit_cast(f16x2, w1.x), acc[c]);
        acc[c] = dot2(xx[5], __builtin_bit_cast(f16x2, w1.y), acc[c]);
        acc[c] = dot2(xx[6], __builtin_bit_cast(f16x2, w1.z), acc[c]);
        acc[c] = dot2(xx[7], __builtin_bit_cast(f16x2, w1.w), acc[c]);
      }
      #pragma unroll
      for (int c = 0; c < 4; ++c) part[js * 256 + c * 64 + cg] = acc[c];
    }
    __syncthreads();  // b3

    // ---- P4: h = tanh(.); write out
    if (t < 256) {
      float v = bh_l[t];
      #pragma unroll
      for (int s = 0; s < 16; ++s) v += part[s * 256 + t];
      v = ftanh(v);
      h_l[t] = v;
      out[((size_t)b * Tt + step) * 256 + t] = v;
    }
    __syncthreads();  // b4

    // ---- P5/P6: big4 + reduce from new h
    phase_big4();
    __syncthreads();  // b5
    phase_reduce();
    __syncthreads();  // b6

    // ---- P7: content dots + row normsq fused (8 rows/thread)
    {
      const int head = t >> 9;            // waves 0-7: head0, 8-15: head1
      const int u = t & 511;
      const int cc = u & 31, ns = u >> 5; // 16 row-slices of 8 rows
      const float4 k4 = *reinterpret_cast<const float4*>(&kbuf[head * 128 + cc * 4]);
      float dsum[8], qsum[8];
      #pragma unroll
      for (int ii = 0; ii < 8; ++ii) {
        const int n = ns * 8 + ii;
        const float4 m4 = *reinterpret_cast<const float4*>(&mem[n * 128 + cc * 4]);
        dsum[ii] = k4.x * m4.x + k4.y * m4.y + k4.z * m4.z + k4.w * m4.w;
        qsum[ii] = m4.x * m4.x + m4.y * m4.y + m4.z * m4.z + m4.w * m4.w;
      }
      #pragma unroll
      for (int ii = 0; ii < 8; ++ii) dsum[ii] = halfsum(dsum[ii]);
      if (head == 0) {
        #pragma unroll
        for (int ii = 0; ii < 8; ++ii) qsum[ii] = halfsum(qsum[ii]);
      }
      if ((lane & 31) == 31) {
        #pragma unroll
        for (int ii = 0; ii < 8; ++ii) dotv[head * 128 + ns * 8 + ii] = dsum[ii];
        if (head == 0) {
          #pragma unroll
          for (int ii = 0; ii < 8; ++ii) normsq[ns * 8 + ii] = qsum[ii];
        }
      }
    }
    __syncthreads();  // b7

    // ---- P8: addressing tail, wave0=head0, wave1=head1 (DPP all-reduces)
    if (wave < 2) {
      const int head = wave;
      const int h6 = head * 6;
      const float beta  = fsoftplus(scal[h6]);
      const float g     = fsigmoid(scal[h6 + 1]);
      const float gamma = 1.f + fsoftplus(scal[h6 + 2]);
      float e0 = scal[h6 + 3], e1 = scal[h6 + 4], e2 = scal[h6 + 5];
      const float mx3 = fmaxf(e0, fmaxf(e1, e2));
      float x0 = expf(e0 - mx3), x1 = expf(e1 - mx3), x2 = expf(e2 - mx3);
      const float si = 1.f / (x0 + x1 + x2);
      const float s0 = x0 * si, s1 = x1 * si, s2 = x2 * si;
      const float knorm = sqrtf(red2[2 * head] + red2[2 * head + 1]);
      float* wprev = head ? ww : wr;
      const int n0 = 2 * lane, n1 = 2 * lane + 1;
      float l0 = beta * dotv[head * 128 + n0] / (knorm * sqrtf(normsq[n0]) + EPSF);
      float l1 = beta * dotv[head * 128 + n1] / (knorm * sqrtf(normsq[n1]) + EPSF);
      const float mx = allmax(fmaxf(l0, l1));
      float q0 = expf(l0 - mx), q1 = expf(l1 - mx);
      const float inv = 1.f / allsum(q0 + q1);
      const float wg0 = g * q0 * inv + (1.f - g) * wprev[n0];
      const float wg1 = g * q1 * inv + (1.f - g) * wprev[n1];
      const float wgl = __shfl(wg1, (lane + 63) & 63);
      const float wgr = __shfl(wg0, (lane + 1) & 63);
      const float sh0 = s0 * wgl + s1 * wg0 + s2 * wg1;
      const float sh1 = s0 * wg0 + s1 * wg1 + s2 * wgr;
      const float wp0 = exp2f(gamma * log2f(sh0));
      const float wp1 = exp2f(gamma * log2f(sh1));
      const float itot = 1.f / (allsum(wp0 + wp1) + EPSF);
      wprev[n0] = wp0 * itot;
      wprev[n1] = wp1 * itot;
    }
    __syncthreads();  // b8
  }
}

extern "C" void kernel_launch(void* const* d_in, const int* in_sizes, int n_in,
                              void* d_out, int out_size, void* d_ws, size_t ws_size,
                              hipStream_t stream) {
  const float* x    = (const float*)d_in[0];
  const float* mem0 = (const float*)d_in[1];
  const float* wr0  = (const float*)d_in[2];
  const float* ww0  = (const float*)d_in[3];
  const float* h0   = (const float*)d_in[4];
  const float* Wx   = (const float*)d_in[5];
  const float* Wrd  = (const float*)d_in[6];
  const float* bh   = (const float*)d_in[7];
  const float* Wk   = (const float*)d_in[8];
  const float* bk   = (const float*)d_in[9];
  const float* Wb   = (const float*)d_in[10];
  const float* bb   = (const float*)d_in[11];
  const float* Wg   = (const float*)d_in[12];
  const float* bg   = (const float*)d_in[13];
  const float* Ws   = (const float*)d_in[14];
  const float* bs   = (const float*)d_in[15];
  const float* Wgam = (const float*)d_in[16];
  const float* bgam = (const float*)d_in[17];
  const float* We   = (const float*)d_in[18];
  const float* be   = (const float*)d_in[19];
  const float* Wa   = (const float*)d_in[20];
  const float* ba   = (const float*)d_in[21];
  float* out = (float*)d_out;
  unsigned int* wsb = (unsigned int*)d_ws;   // 98304 uints = 384 KB

  hipLaunchKernelGGL(ntm_prep, dim3(384), dim3(256), 0, stream, We, Wa, Wk, Wx, Wrd, wsb);
  hipLaunchKernelGGL(ntm_kernel, dim3(128), dim3(NT), 0, stream,
                     x, mem0, wr0, ww0, h0, bh, bk, Wb, bb,
                     Wg, bg, Ws, bs, Wgam, bgam, be, ba,
                     (const uint4*)wsb, out);
}

// Round 12
// 1120.412 us; speedup vs baseline: 1.0655x; 1.0655x over previous
//
#include <hip/hip_runtime.h>
#include <math.h>

#define Tt 128
#define NT 256
#define EPSF 1e-8f
#define WC_OFF 65536   // u32 offset of C-matmul weights in wsb

typedef _Float16 f16x2 __attribute__((ext_vector_type(2)));

__device__ __forceinline__ float fsigmoid(float v) { return 1.f / (1.f + expf(-v)); }
__device__ __forceinline__ float fsoftplus(float v) { return (v > 20.f) ? v : log1pf(expf(v)); }
__device__ __forceinline__ float ftanh(float v) { float e = expf(2.f * v); return 1.f - 2.f / (e + 1.f); }

__device__ __forceinline__ float dot2(f16x2 a, f16x2 b, float c) {
#if __has_builtin(__builtin_amdgcn_fdot2)
  return __builtin_amdgcn_fdot2(a, b, c, false);
#else
  return c + (float)a.x * (float)b.x + (float)a.y * (float)b.y;
#endif
}
__device__ __forceinline__ f16x2 pack2(float a, float b) {
  f16x2 p; p.x = (_Float16)a; p.y = (_Float16)b; return p;
}

// ---- DPP reduction primitives ----
template <int C> __device__ __forceinline__ float dppadd(float v) {
  int s = __builtin_amdgcn_update_dpp(0, __builtin_bit_cast(int, v), C, 0xf, 0xf, true);
  return v + __builtin_bit_cast(float, s);
}
template <int C> __device__ __forceinline__ float dppmax(float v) {
  int iv = __builtin_bit_cast(int, v);
  int s = __builtin_amdgcn_update_dpp(iv, iv, C, 0xf, 0xf, false);
  return fmaxf(v, __builtin_bit_cast(float, s));
}
__device__ __forceinline__ float qsum16(float v) {  // sum within 16-lane rows
  v = dppadd<0x111>(v); v = dppadd<0x112>(v); v = dppadd<0x114>(v); v = dppadd<0x118>(v);
  return v;
}
__device__ __forceinline__ float halfsum(float v) {  // lane31/lane63 hold 32-lane sums
  v = qsum16(v); v = dppadd<0x142>(v);
  return v;
}
__device__ __forceinline__ float allsum(float v) {
  v = halfsum(v); v = dppadd<0x143>(v);
  return __builtin_bit_cast(float, __builtin_amdgcn_readlane(__builtin_bit_cast(int, v), 63));
}
__device__ __forceinline__ float allmax(float v) {
  v = dppmax<0x111>(v); v = dppmax<0x112>(v); v = dppmax<0x114>(v);
  v = dppmax<0x118>(v); v = dppmax<0x142>(v); v = dppmax<0x143>(v);
  return __builtin_bit_cast(float, __builtin_amdgcn_readlane(__builtin_bit_cast(int, v), 63));
}

// ===== prep: pack weights f32 -> f16x2, NT=256 register-resident layout =====
// big4 [0,65536):  i = (((c*4+js)*8+q)*64+cg)*4+e ; jj=q*4+e; row0=js*64+2*jj (h 256)
//   col=(c&1)*64+cg; mat=c>>1 in [We|Wa|Wk0|Wk1]
// wc [65536,98304): j = (((c2*4+js)*8+q)*64+cg)*4+e ; row0=js*64+2*jj ([x|r] 256)
//   col=c2*64+cg; row0<128 -> Wx else Wrd
__global__ __launch_bounds__(256, 1) void ntm_prep(
    const float* __restrict__ We, const float* __restrict__ Wa,
    const float* __restrict__ Wk, const float* __restrict__ Wx,
    const float* __restrict__ Wrd, unsigned int* __restrict__ wsb)
{
  const int i = blockIdx.x * 256 + threadIdx.x;   // grid 384*256 = 98304
  if (i < 65536) {
    const int e = i & 3;
    const int cg = (i >> 2) & 63;
    const int q = (i >> 8) & 7;
    const int js = (i >> 11) & 3;
    const int c = (i >> 13) & 7;
    const int jj = q * 4 + e;
    const int row0 = js * 64 + 2 * jj;
    const int col = (c & 1) * 64 + cg;
    const int mat = c >> 1;
    const float* base = (mat == 0) ? We : (mat == 1) ? Wa : (mat == 2) ? Wk : (Wk + 256 * 128);
    wsb[i] = __builtin_bit_cast(unsigned int, pack2(base[row0 * 128 + col], base[(row0 + 1) * 128 + col]));
  } else {
    const int j = i - WC_OFF;
    const int e = j & 3;
    const int cg = (j >> 2) & 63;
    const int q = (j >> 8) & 7;
    const int js = (j >> 11) & 3;
    const int c2 = (j >> 13) & 3;
    const int jj = q * 4 + e;
    const int row0 = js * 64 + 2 * jj;
    const int col = c2 * 64 + cg;
    float v0, v1;
    if (row0 < 128) { v0 = Wx[row0 * 256 + col]; v1 = Wx[(row0 + 1) * 256 + col]; }
    else            { v0 = Wrd[(row0 - 128) * 256 + col]; v1 = Wrd[(row0 - 127) * 256 + col]; }
    wsb[i] = __builtin_bit_cast(unsigned int, pack2(v0, v1));
  }
}

__global__ __launch_bounds__(NT, 1) void ntm_kernel(
    const float* __restrict__ x, const float* __restrict__ mem0,
    const float* __restrict__ wr0, const float* __restrict__ ww0,
    const float* __restrict__ h0, const float* __restrict__ bh,
    const float* __restrict__ bk,
    const float* __restrict__ Wb, const float* __restrict__ bb,
    const float* __restrict__ Wg, const float* __restrict__ bg,
    const float* __restrict__ Ws, const float* __restrict__ bs,
    const float* __restrict__ Wgam, const float* __restrict__ bgam,
    const float* __restrict__ be, const float* __restrict__ ba,
    const uint4* __restrict__ wsb4,
    float* __restrict__ out)
{
  const int b = blockIdx.x;
  const int t = threadIdx.x;
  const int lane = t & 63;
  const int wave = t >> 6;
  const int cg = t & 63;    // matmul column lane
  const int js = t >> 6;    // inner-dim slice (4 slices of 64)
  const int c4 = t & 31;    // float4 column group for mem passes
  const int rs = t >> 5;    // row slice for mem passes (8 slices)

  __shared__ __align__(16) float mem[128 * 128];   // 64 KB
  __shared__ __align__(16) float part[2048];       // 8 KB
  __shared__ __align__(16) float h_l[256];
  __shared__ __align__(16) float xf[128];
  __shared__ __align__(16) float rf[128];
  __shared__ __align__(16) float er[128];
  __shared__ __align__(16) float ad[128];
  __shared__ __align__(16) float kbuf[256];
  __shared__ float wsm_l[3072];
  __shared__ float wr[128], ww[128];
  __shared__ float normsq[128];
  __shared__ float dotv[256];
  __shared__ float scal[12];
  __shared__ float red2[4];
  __shared__ float bias_big[512];                  // [be | ba | bk0 | bk1]
  __shared__ float bh_l[256];
  __shared__ float bias_sm[12];

  // ===== ALL weights register-resident: big4 = 64 uint4 (256 regs), wc = 32 uint4 (128 regs)
  uint4 wbig4[64];
  {
    #pragma unroll
    for (int c = 0; c < 8; ++c)
      #pragma unroll
      for (int q = 0; q < 8; ++q)
        wbig4[c * 8 + q] = wsb4[((c * 4 + js) * 8 + q) * 64 + cg];
  }
  uint4 wc4[32];
  {
    #pragma unroll
    for (int c = 0; c < 4; ++c)
      #pragma unroll
      for (int q = 0; q < 8; ++q)
        wc4[c * 8 + q] = wsb4[(WC_OFF / 4) + ((c * 4 + js) * 8 + q) * 64 + cg];
  }

  // ===== state / bias / small-weight init =====
  for (int i = t; i < 4096; i += NT)
    reinterpret_cast<float4*>(mem)[i] = reinterpret_cast<const float4*>(mem0)[i];
  if (t < 128) { wr[t] = wr0[b * 128 + t]; ww[t] = ww0[b * 128 + t]; }
  h_l[t] = h0[b * 256 + t]; bh_l[t] = bh[t];
  bias_big[t] = (t < 128) ? be[t] : ba[t - 128];
  bias_big[t + 256] = bk[t];
  for (int i = t; i < 3072; i += NT) {
    const int d = i >> 8, j = i & 255;
    const int head = d / 6, kind = d % 6;
    float v;
    if (kind == 0)      v = Wb[head * 256 + j];
    else if (kind == 1) v = Wg[head * 256 + j];
    else if (kind == 2) v = Wgam[head * 256 + j];
    else                v = Ws[head * 768 + j * 3 + (kind - 3)];
    wsm_l[i] = v;
  }
  if (t < 12) {
    const int head = t / 6, kind = t % 6;
    bias_sm[t] = (kind == 0) ? bb[head] : (kind == 1) ? bg[head]
               : (kind == 2) ? bgam[head] : bs[head * 3 + (kind - 3)];
  }
  __syncthreads();

  // ---- big4 matmul partials from h_l, register-resident weights
  auto phase_big4 = [&]() {
    float acc[8];
    #pragma unroll
    for (int c = 0; c < 8; ++c) acc[c] = 0.f;
    #pragma unroll
    for (int q = 0; q < 8; ++q) {
      f16x2 hh[4];
      #pragma unroll
      for (int e = 0; e < 4; ++e) {
        const float2 h2 = *reinterpret_cast<const float2*>(&h_l[js * 64 + (q * 4 + e) * 2]);
        hh[e] = pack2(h2.x, h2.y);
      }
      #pragma unroll
      for (int c = 0; c < 8; ++c) {
        const uint4 w = wbig4[c * 8 + q];
        acc[c] = dot2(hh[0], __builtin_bit_cast(f16x2, w.x), acc[c]);
        acc[c] = dot2(hh[1], __builtin_bit_cast(f16x2, w.y), acc[c]);
        acc[c] = dot2(hh[2], __builtin_bit_cast(f16x2, w.z), acc[c]);
        acc[c] = dot2(hh[3], __builtin_bit_cast(f16x2, w.w), acc[c]);
      }
    }
    #pragma unroll
    for (int c = 0; c < 8; ++c) part[js * 512 + c * 64 + cg] = acc[c];
  };

  // ---- reduce big4 -> er/ad/kbuf + k^2 (DPP) + 12 small dots (16-lane DPP)
  auto phase_reduce = [&]() {
    {
      float v0 = bias_big[t];
      float v1 = bias_big[t + 256];
      #pragma unroll
      for (int s = 0; s < 4; ++s) { v0 += part[s * 512 + t]; v1 += part[s * 512 + t + 256]; }
      if (t < 128) er[t] = fsigmoid(v0);
      else         ad[t - 128] = ftanh(v0);
      float kv = ftanh(v1);
      kbuf[t] = kv;
      float ks = kv * kv;
      ks = halfsum(ks); ks = dppadd<0x143>(ks);
      if (lane == 63) red2[wave] = ks;
    }
    if (t < 192) {
      const int d = t >> 4, l4 = t & 15;
      float s = 0.f;
      #pragma unroll
      for (int q = 0; q < 16; ++q) s += h_l[l4 + 16 * q] * wsm_l[d * 256 + l4 + 16 * q];
      s = qsum16(s);
      if ((lane & 15) == 15) scal[d] = s + bias_sm[d];
    }
  };

  // prologue: er/ad/k/scal for step 0 from h0
  phase_big4();
  __syncthreads();
  phase_reduce();
  __syncthreads();

  for (int step = 0; step < Tt; ++step) {
    // ---- P1: x_t -> xf; mem erase/add; per-row normsq (DPP); r partials (16 rows/thread)
    if (t < 128) xf[t] = x[((size_t)b * Tt + step) * 128 + t];
    {
      const float4 e4 = *reinterpret_cast<const float4*>(&er[c4 * 4]);
      const float4 a4 = *reinterpret_cast<const float4*>(&ad[c4 * 4]);
      float rx = 0.f, ry = 0.f, rz = 0.f, rw = 0.f;
      #pragma unroll
      for (int k = 0; k < 16; ++k) {
        const int n = rs + 8 * k;
        const float wwn = ww[n], wrn = wr[n];
        float4 v = *reinterpret_cast<const float4*>(&mem[n * 128 + c4 * 4]);
        v.x = v.x * (1.f - wwn * e4.x) + wwn * a4.x;
        v.y = v.y * (1.f - wwn * e4.y) + wwn * a4.y;
        v.z = v.z * (1.f - wwn * e4.z) + wwn * a4.z;
        v.w = v.w * (1.f - wwn * e4.w) + wwn * a4.w;
        *reinterpret_cast<float4*>(&mem[n * 128 + c4 * 4]) = v;
        float nsq = v.x * v.x + v.y * v.y + v.z * v.z + v.w * v.w;
        nsq = halfsum(nsq);
        if ((lane & 31) == 31) normsq[n] = nsq;
        rx += wrn * v.x; ry += wrn * v.y; rz += wrn * v.z; rw += wrn * v.w;
      }
      *reinterpret_cast<float4*>(&part[rs * 128 + c4 * 4]) = make_float4(rx, ry, rz, rw);
    }
    __syncthreads();  // b1

    // ---- P2: reduce r partials (8 slices)
    if (t < 128) {
      float r = 0.f;
      #pragma unroll
      for (int s = 0; s < 8; ++s) r += part[s * 128 + t];
      rf[t] = r;
    }
    __syncthreads();  // b2

    // ---- P3: C-matmul partials from [xf|rf], register-resident weights
    {
      const float* src = (js < 2) ? (xf + js * 64) : (rf + (js - 2) * 64);
      float acc[4];
      #pragma unroll
      for (int c = 0; c < 4; ++c) acc[c] = 0.f;
      #pragma unroll
      for (int q = 0; q < 8; ++q) {
        f16x2 xx[4];
        #pragma unroll
        for (int e = 0; e < 4; ++e) {
          const float2 s2 = *reinterpret_cast<const float2*>(&src[(q * 4 + e) * 2]);
          xx[e] = pack2(s2.x, s2.y);
        }
        #pragma unroll
        for (int c = 0; c < 4; ++c) {
          const uint4 w = wc4[c * 8 + q];
          acc[c] = dot2(xx[0], __builtin_bit_cast(f16x2, w.x), acc[c]);
          acc[c] = dot2(xx[1], __builtin_bit_cast(f16x2, w.y), acc[c]);
          acc[c] = dot2(xx[2], __builtin_bit_cast(f16x2, w.z), acc[c]);
          acc[c] = dot2(xx[3], __builtin_bit_cast(f16x2, w.w), acc[c]);
        }
      }
      #pragma unroll
      for (int c = 0; c < 4; ++c) part[js * 256 + c * 64 + cg] = acc[c];
    }
    __syncthreads();  // b3

    // ---- P4: h = tanh(.); write out
    {
      float v = bh_l[t];
      #pragma unroll
      for (int s = 0; s < 4; ++s) v += part[s * 256 + t];
      v = ftanh(v);
      h_l[t] = v;
      out[((size_t)b * Tt + step) * 256 + t] = v;
    }
    __syncthreads();  // b4

    // ---- P5/P6: big4 + reduce from new h
    phase_big4();
    __syncthreads();  // b5
    phase_reduce();
    __syncthreads();  // b6

    // ---- P7: content dots (32 rows/thread, chunks of 8)
    {
      const int head = t >> 7;            // waves 0-1: head0, 2-3: head1
      const int u = t & 127;
      const int cc = u & 31, ns = u >> 5; // 4 row-slices of 32 rows
      const float4 k4 = *reinterpret_cast<const float4*>(&kbuf[head * 128 + cc * 4]);
      #pragma unroll
      for (int ch = 0; ch < 4; ++ch) {
        float dsum[8];
        #pragma unroll
        for (int ii = 0; ii < 8; ++ii) {
          const int n = ns * 32 + ch * 8 + ii;
          const float4 m4 = *reinterpret_cast<const float4*>(&mem[n * 128 + cc * 4]);
          dsum[ii] = k4.x * m4.x + k4.y * m4.y + k4.z * m4.z + k4.w * m4.w;
        }
        #pragma unroll
        for (int ii = 0; ii < 8; ++ii) dsum[ii] = halfsum(dsum[ii]);
        if ((lane & 31) == 31) {
          #pragma unroll
          for (int ii = 0; ii < 8; ++ii) dotv[head * 128 + ns * 32 + ch * 8 + ii] = dsum[ii];
        }
      }
    }
    __syncthreads();  // b7

    // ---- P8: addressing tail, wave0=head0, wave1=head1 (DPP all-reduces)
    if (wave < 2) {
      const int head = wave;
      const int h6 = head * 6;
      const float beta  = fsoftplus(scal[h6]);
      const float g     = fsigmoid(scal[h6 + 1]);
      const float gamma = 1.f + fsoftplus(scal[h6 + 2]);
      float e0 = scal[h6 + 3], e1 = scal[h6 + 4], e2 = scal[h6 + 5];
      const float mx3 = fmaxf(e0, fmaxf(e1, e2));
      float x0 = expf(e0 - mx3), x1 = expf(e1 - mx3), x2 = expf(e2 - mx3);
      const float si = 1.f / (x0 + x1 + x2);
      const float s0 = x0 * si, s1 = x1 * si, s2 = x2 * si;
      const float knorm = sqrtf(red2[2 * head] + red2[2 * head + 1]);
      float* wprev = head ? ww : wr;
      const int n0 = 2 * lane, n1 = 2 * lane + 1;
      float l0 = beta * dotv[head * 128 + n0] / (knorm * sqrtf(normsq[n0]) + EPSF);
      float l1 = beta * dotv[head * 128 + n1] / (knorm * sqrtf(normsq[n1]) + EPSF);
      const float mx = allmax(fmaxf(l0, l1));
      float q0 = expf(l0 - mx), q1 = expf(l1 - mx);
      const float inv = 1.f / allsum(q0 + q1);
      const float wg0 = g * q0 * inv + (1.f - g) * wprev[n0];
      const float wg1 = g * q1 * inv + (1.f - g) * wprev[n1];
      const float wgl = __shfl(wg1, (lane + 63) & 63);
      const float wgr = __shfl(wg0, (lane + 1) & 63);
      const float sh0 = s0 * wgl + s1 * wg0 + s2 * wg1;
      const float sh1 = s0 * wg0 + s1 * wg1 + s2 * wgr;
      const float wp0 = exp2f(gamma * log2f(sh0));
      const float wp1 = exp2f(gamma * log2f(sh1));
      const float itot = 1.f / (allsum(wp0 + wp1) + EPSF);
      wprev[n0] = wp0 * itot;
      wprev[n1] = wp1 * itot;
    }
    __syncthreads();  // b8
  }
}

extern "C" void kernel_launch(void* const* d_in, const int* in_sizes, int n_in,
                              void* d_out, int out_size, void* d_ws, size_t ws_size,
                              hipStream_t stream) {
  const float* x    = (const float*)d_in[0];
  const float* mem0 = (const float*)d_in[1];
  const float* wr0  = (const float*)d_in[2];
  const float* ww0  = (const float*)d_in[3];
  const float* h0   = (const float*)d_in[4];
  const float* Wx   = (const float*)d_in[5];
  const float* Wrd  = (const float*)d_in[6];
  const float* bh   = (const float*)d_in[7];
  const float* Wk   = (const float*)d_in[8];
  const float* bk   = (const float*)d_in[9];
  const float* Wb   = (const float*)d_in[10];
  const float* bb   = (const float*)d_in[11];
  const float* Wg   = (const float*)d_in[12];
  const float* bg   = (const float*)d_in[13];
  const float* Ws   = (const float*)d_in[14];
  const float* bs   = (const float*)d_in[15];
  const float* Wgam = (const float*)d_in[16];
  const float* bgam = (const float*)d_in[17];
  const float* We   = (const float*)d_in[18];
  const float* be   = (const float*)d_in[19];
  const float* Wa   = (const float*)d_in[20];
  const float* ba   = (const float*)d_in[21];
  float* out = (float*)d_out;
  unsigned int* wsb = (unsigned int*)d_ws;   // 98304 uints = 384 KB

  hipLaunchKernelGGL(ntm_prep, dim3(384), dim3(256), 0, stream, We, Wa, Wk, Wx, Wrd, wsb);
  hipLaunchKernelGGL(ntm_kernel, dim3(128), dim3(NT), 0, stream,
                     x, mem0, wr0, ww0, h0, bh, bk, Wb, bb,
                     Wg, bg, Ws, bs, Wgam, bgam, be, ba,
                     (const uint4*)wsb, out);
}